// Round 13
// baseline (230.987 us; speedup 1.0000x reference)
//
#include <hip/hip_runtime.h>
#include <math.h>

#define B 8
#define T 8192
#define D 512
#define M 512
#define CHUNK 4
#define NCHUNK (T / CHUNK)     // 2048 fine chunks per batch
#define GRP 32                 // fine chunks per coarse group
#define NGRP (NCHUNK / GRP)    // 64 groups per batch
#define BM (B * M)             // 4096
#define KD 512                 // GEMM K (fourier part hoisted out)

typedef __attribute__((ext_vector_type(8))) short short8;
typedef __attribute__((ext_vector_type(4))) short short4v;
typedef __attribute__((ext_vector_type(4))) float floatx4;

static __device__ inline unsigned short f2bf(float f) {
    unsigned int u = __float_as_uint(f);
    unsigned int r = (u + 0x7fffu + ((u >> 16) & 1u)) >> 16;   // RNE
    return (unsigned short)r;
}

// ================= KA: fused {chunk-scan | wsplit | ffout} ==================
// Scan: 256 blocks, each half-block (128 thr) owns one group, float4 loads.
// Single-bf16 W (no lo-split): error budget analysis says RNE bf16 on X and W
// adds ~0.003-0.01 absmax vs the 0.059 threshold.
__global__ __launch_bounds__(256) void k_fusedA(const float* __restrict__ fe,
                                                const float* __restrict__ W,
                                                const float* __restrict__ bias,
                                                float* __restrict__ cp,
                                                float* __restrict__ gsum,
                                                short* __restrict__ WhT,
                                                float* __restrict__ ffout) {
    int blk = blockIdx.x;
    int tid = threadIdx.x;
    if (blk < 256) {
        // ---- chunk-scan: gg = global group id, 128 rows, full D via float4
        int gg = (blk << 1) | (tid >> 7);      // 0..511
        int b = gg >> 6;
        int g = gg & 63;
        int ht = tid & 127;
        int d4 = ht << 2;
        const float* src = fe + ((size_t)(b * T + g * (GRP * CHUNK)) * D + d4);
        float* cpb = cp + ((size_t)b * NCHUNK + (size_t)g * GRP) * D + d4;
        float4 acc = {0.f, 0.f, 0.f, 0.f};
#pragma unroll 4
        for (int c = 0; c < GRP; ++c) {
#pragma unroll
            for (int r = 0; r < CHUNK; ++r) {
                float4 v = *(const float4*)(src + (size_t)(c * CHUNK + r) * D);
                acc.x += v.x; acc.y += v.y; acc.z += v.z; acc.w += v.w;
            }
            *(float4*)(cpb + (size_t)c * D) = acc;
        }
        *(float4*)(gsum + ((size_t)b * NGRP + g) * D + d4) = acc;
    } else if (blk < 384) {
        // ---- wsplit: W[512x512] -> WhT (bf16, transposed)
        __shared__ float ws[32][65];
        int wb = blk - 256;
        int k0 = (wb & 15) * 32;
        int n0 = (wb >> 4) * 64;
        {
            int kk = tid >> 3;
            int nn = (tid & 7) << 3;
            const float* src = W + (size_t)(k0 + kk) * D + n0 + nn;
            float4 v0 = *(const float4*)src;
            float4 v1 = *(const float4*)(src + 4);
            ws[kk][nn + 0] = v0.x; ws[kk][nn + 1] = v0.y; ws[kk][nn + 2] = v0.z; ws[kk][nn + 3] = v0.w;
            ws[kk][nn + 4] = v1.x; ws[kk][nn + 5] = v1.y; ws[kk][nn + 6] = v1.z; ws[kk][nn + 7] = v1.w;
        }
        __syncthreads();
        int n = tid >> 2;
        int kq = (tid & 3) << 3;
        short8 hv;
#pragma unroll
        for (int j = 0; j < 8; ++j) {
            hv[j] = (short)f2bf(ws[kq + j][n]);
        }
        *(short8*)(WhT + (size_t)(n0 + n) * KD + k0 + kq) = hv;
    } else {
        // ---- ffout: 2 m per block (exact fp32 fourier part)
        int m = ((blk - 384) << 1) + (tid >> 7);
        int n4 = (tid & 127) << 2;
        float pos = (float)m * (1.0f / 511.0f);
        float4 acc = *(const float4*)(bias + n4);
#pragma unroll
        for (int j = 0; j < 16; ++j) {
            float freq = expf(0.46051701859880914f * (float)j);  // 1000^(j/15)
            float ang = pos * freq;
            float s = sinf(ang), c = cosf(ang);
            float4 wsn = *(const float4*)(W + (size_t)(D + j) * D + n4);
            float4 wcn = *(const float4*)(W + (size_t)(D + 16 + j) * D + n4);
            acc.x += s * wsn.x + c * wcn.x;
            acc.y += s * wsn.y + c * wcn.y;
            acc.z += s * wsn.z + c * wcn.z;
            acc.w += s * wsn.w + c * wcn.w;
        }
        *(float4*)(ffout + (size_t)m * D + n4) = acc;
    }
}

// ================= KB: segment means -> X [4096][512] bf16 ==================
// Coarse prefix computed INLINE from gsum (1 MB, L2-resident) — no separate
// scan_coarse kernel (saves one launch + drain).
__global__ __launch_bounds__(128) void k_buildx(const float* __restrict__ fe,
                                                const int* __restrict__ bounds,
                                                const float* __restrict__ cp,
                                                const float* __restrict__ gsum,
                                                short* __restrict__ X) {
    int bm = blockIdx.x;
    int b = bm >> 9;                            // bm / M
    int b0 = bounds[bm * 2 + 0];
    int b1 = bounds[bm * 2 + 1];
    int s = min(max(b0, 0), T - 1);
    int e = max(min(b1, T), s + 1);
    int cs_ = s >> 2, ce = e >> 2;
    int gcs = cs_ >> 5, gce = ce >> 5;          // coarse group indices (<= 64)
    int d4 = threadIdx.x << 2;

    const float* cpb = cp + (size_t)b * NCHUNK * D;
    const float* gsb = gsum + (size_t)b * NGRP * D + d4;

    // inline coarse exclusive prefix: pcs = sum groups [0,gcs), pce = [0,gce)
    float4 acc = {0.f, 0.f, 0.f, 0.f};
    int g = 0;
    for (; g < gcs; ++g) {
        float4 v = *(const float4*)(gsb + (size_t)g * D);
        acc.x += v.x; acc.y += v.y; acc.z += v.z; acc.w += v.w;
    }
    float4 pcs = acc;
    for (; g < gce; ++g) {
        float4 v = *(const float4*)(gsb + (size_t)g * D);
        acc.x += v.x; acc.y += v.y; acc.z += v.z; acc.w += v.w;
    }
    // acc = exclusive prefix at group gce
    if (ce & 31) {
        float4 v = *(const float4*)(cpb + (size_t)(ce - 1) * D + d4);
        acc.x += v.x; acc.y += v.y; acc.z += v.z; acc.w += v.w;
    }
    acc.x -= pcs.x; acc.y -= pcs.y; acc.z -= pcs.z; acc.w -= pcs.w;
    if (cs_ & 31) {
        float4 v = *(const float4*)(cpb + (size_t)(cs_ - 1) * D + d4);
        acc.x -= v.x; acc.y -= v.y; acc.z -= v.z; acc.w -= v.w;
    }

    const float* feb = fe + (size_t)b * T * D + d4;
    for (int t = ce * CHUNK; t < e; ++t) {           // <= 3 iters
        float4 v = *(const float4*)(feb + (size_t)t * D);
        acc.x += v.x; acc.y += v.y; acc.z += v.z; acc.w += v.w;
    }
    for (int t = cs_ * CHUNK; t < s; ++t) {          // <= 3 iters
        float4 v = *(const float4*)(feb + (size_t)t * D);
        acc.x -= v.x; acc.y -= v.y; acc.z -= v.z; acc.w -= v.w;
    }
    float inv = 1.0f / (float)(e - s);
    short4v hv;
    hv[0] = (short)f2bf(acc.x * inv);
    hv[1] = (short)f2bf(acc.y * inv);
    hv[2] = (short)f2bf(acc.z * inv);
    hv[3] = (short)f2bf(acc.w * inv);
    *(short4v*)(X + (size_t)bm * KD + d4) = hv;
}

// ================= KC: MFMA GEMM, Out = X@W + ffout =========================
// 64x64 block tile, 256 threads (2x2 waves of 32x32), K=512, single bf16.
#define BK 64
__global__ __launch_bounds__(256) void k_gemm(const short* __restrict__ X,
                                              const short* __restrict__ WhT,
                                              const float* __restrict__ ffout,
                                              float* __restrict__ out) {
    __shared__ short Ah[2][64 * 32];
    __shared__ short Bh[2][64 * 32];                 // 16 KB total
    int n0 = (blockIdx.x & 7) << 6;
    int m0 = (blockIdx.x >> 3) << 6;
    int tid = threadIdx.x;
    int w = tid >> 6;
    int l = tid & 63;
    int lm = l & 15;
    int q = l >> 4;
    int wm = (w & 1) << 5;
    int wn = (w >> 1) << 5;

    floatx4 acc[2][2];
#pragma unroll
    for (int i = 0; i < 2; ++i)
#pragma unroll
        for (int j = 0; j < 2; ++j)
            acc[i][j] = (floatx4){0.f, 0.f, 0.f, 0.f};

    int srow = tid >> 2;
    int skq = tid & 3;
    int sslot = skq ^ ((srow >> 1) & 3);
    int ldsoff = (srow << 5) + (sslot << 3);
    const short* gX = X + (size_t)(m0 + srow) * KD + (skq << 3);
    const short* gB = WhT + (size_t)(n0 + srow) * KD + (skq << 3);

    int aoff[2], boff[2];
#pragma unroll
    for (int mt = 0; mt < 2; ++mt) {
        int row = wm + (mt << 4) + lm;
        aoff[mt] = (row << 5) + ((q ^ ((row >> 1) & 3)) << 3);
    }
#pragma unroll
    for (int nt = 0; nt < 2; ++nt) {
        int row = wn + (nt << 4) + lm;
        boff[nt] = (row << 5) + ((q ^ ((row >> 1) & 3)) << 3);
    }

    // prologue prefetch: K-tile 0 (both 32-k halves)
    short8 pxh[2], pbh[2];
#pragma unroll
    for (int h = 0; h < 2; ++h) {
        pxh[h] = *(const short8*)(gX + (h << 5));
        pbh[h] = *(const short8*)(gB + (h << 5));
    }

    for (int k0 = 0; k0 < KD; k0 += BK) {   // 8 iterations
        __syncthreads();
#pragma unroll
        for (int h = 0; h < 2; ++h) {
            *(short8*)(&Ah[h][ldsoff]) = pxh[h];
            *(short8*)(&Bh[h][ldsoff]) = pbh[h];
        }
        __syncthreads();

        // prefetch next K-tile while computing this one
        int kn = k0 + BK;
        if (kn < KD) {
#pragma unroll
            for (int h = 0; h < 2; ++h) {
                pxh[h] = *(const short8*)(gX + kn + (h << 5));
                pbh[h] = *(const short8*)(gB + kn + (h << 5));
            }
        }

#pragma unroll
        for (int h = 0; h < 2; ++h) {
            short8 ah[2], bh[2];
#pragma unroll
            for (int mt = 0; mt < 2; ++mt)
                ah[mt] = *(const short8*)(&Ah[h][aoff[mt]]);
#pragma unroll
            for (int nt = 0; nt < 2; ++nt)
                bh[nt] = *(const short8*)(&Bh[h][boff[nt]]);
#pragma unroll
            for (int mt = 0; mt < 2; ++mt)
#pragma unroll
                for (int nt = 0; nt < 2; ++nt)
                    acc[mt][nt] = __builtin_amdgcn_mfma_f32_16x16x32_bf16(
                        ah[mt], bh[nt], acc[mt][nt], 0, 0, 0);
        }
    }

#pragma unroll
    for (int mt = 0; mt < 2; ++mt) {
#pragma unroll
        for (int nt = 0; nt < 2; ++nt) {
            int gcol = n0 + wn + (nt << 4) + lm;
#pragma unroll
            for (int r = 0; r < 4; ++r) {
                int grow = m0 + wm + (mt << 4) + (q << 2) + r;
                float f = ffout[(size_t)(grow & (M - 1)) * D + gcol];
                out[(size_t)grow * D + gcol] = acc[mt][nt][r] + f;
            }
        }
    }
}

extern "C" void kernel_launch(void* const* d_in, const int* in_sizes, int n_in,
                              void* d_out, int out_size, void* d_ws, size_t ws_size,
                              hipStream_t stream) {
    const float* fe = (const float*)d_in[0];
    const int* bounds = (const int*)d_in[1];
    const float* W = (const float*)d_in[2];
    const float* bias = (const float*)d_in[3];
    float* out = (float*)d_out;

    float* cp = (float*)d_ws;                                  // 33.5 MB
    float* gsum = cp + (size_t)B * NCHUNK * D;                 // 1 MB
    float* ffout = gsum + (size_t)B * NGRP * D;                // 1 MB
    short* X = (short*)(ffout + (size_t)M * D);                // 4 MB
    short* WhT = X + (size_t)BM * KD;                          // 0.5 MB

    k_fusedA<<<640, 256, 0, stream>>>(fe, W, bias, cp, gsum, WhT, ffout);
    k_buildx<<<BM, 128, 0, stream>>>(fe, bounds, cp, gsum, X);
    k_gemm<<<64 * 8, 256, 0, stream>>>(X, WhT, ffout, out);
}

// Round 15
// 227.738 us; speedup vs baseline: 1.0143x; 1.0143x over previous
//
#include <hip/hip_runtime.h>
#include <math.h>

#define B 8
#define T 8192
#define D 512
#define M 512
#define CHUNK 4
#define NCHUNK (T / CHUNK)     // 2048 fine chunks per batch
#define GRP 32                 // fine chunks per coarse group
#define NGRP (NCHUNK / GRP)    // 64 groups per batch
#define BM (B * M)             // 4096
#define KD 512                 // GEMM K (fourier part hoisted out)

typedef __attribute__((ext_vector_type(8))) short short8;
typedef __attribute__((ext_vector_type(4))) short short4v;
typedef __attribute__((ext_vector_type(4))) float floatx4;

static __device__ inline unsigned short f2bf(float f) {
    unsigned int u = __float_as_uint(f);
    unsigned int r = (u + 0x7fffu + ((u >> 16) & 1u)) >> 16;   // RNE
    return (unsigned short)r;
}

// ================= KA: fused {chunk-scan | wsplit | ffout} ==================
// Scan: 8-chunk register tiles -> 32 independent loads, short register prefix,
// batched stores. Dependent-chain length 128 -> ~36 fadds.
__global__ __launch_bounds__(256) void k_fusedA(const float* __restrict__ fe,
                                                const float* __restrict__ W,
                                                const float* __restrict__ bias,
                                                float* __restrict__ cp,
                                                float* __restrict__ gsum,
                                                short* __restrict__ WhT,
                                                float* __restrict__ ffout) {
    int blk = blockIdx.x;
    int tid = threadIdx.x;
    if (blk < 256) {
        // ---- chunk-scan: gg = global group id, 128 lanes over D (float4)
        int gg = (blk << 1) | (tid >> 7);      // 0..511
        int b = gg >> 6;
        int g = gg & 63;
        int ht = tid & 127;
        int d4 = ht << 2;
        const float* src = fe + ((size_t)(b * T + g * (GRP * CHUNK)) * D + d4);
        float* cpb = cp + ((size_t)b * NCHUNK + (size_t)g * GRP) * D + d4;
        float4 carry = {0.f, 0.f, 0.f, 0.f};
#pragma unroll
        for (int tile = 0; tile < 4; ++tile) {
            float4 ts[8];
#pragma unroll
            for (int c = 0; c < 8; ++c) {
                const float* p = src + (size_t)((tile * 8 + c) * CHUNK) * D;
                float4 r0 = *(const float4*)(p);
                float4 r1 = *(const float4*)(p + (size_t)D);
                float4 r2 = *(const float4*)(p + (size_t)(2 * D));
                float4 r3 = *(const float4*)(p + (size_t)(3 * D));
                float4 s01, s23;
                s01.x = r0.x + r1.x; s01.y = r0.y + r1.y; s01.z = r0.z + r1.z; s01.w = r0.w + r1.w;
                s23.x = r2.x + r3.x; s23.y = r2.y + r3.y; s23.z = r2.z + r3.z; s23.w = r2.w + r3.w;
                ts[c].x = s01.x + s23.x; ts[c].y = s01.y + s23.y;
                ts[c].z = s01.z + s23.z; ts[c].w = s01.w + s23.w;
            }
            ts[0].x += carry.x; ts[0].y += carry.y; ts[0].z += carry.z; ts[0].w += carry.w;
#pragma unroll
            for (int c = 1; c < 8; ++c) {
                ts[c].x += ts[c - 1].x; ts[c].y += ts[c - 1].y;
                ts[c].z += ts[c - 1].z; ts[c].w += ts[c - 1].w;
            }
#pragma unroll
            for (int c = 0; c < 8; ++c)
                *(float4*)(cpb + (size_t)((tile * 8 + c)) * D) = ts[c];
            carry = ts[7];
        }
        *(float4*)(gsum + ((size_t)b * NGRP + g) * D + d4) = carry;
    } else if (blk < 384) {
        // ---- wsplit: W[512x512] -> WhT (bf16, transposed)
        __shared__ float ws[32][65];
        int wb = blk - 256;
        int k0 = (wb & 15) * 32;
        int n0 = (wb >> 4) * 64;
        {
            int kk = tid >> 3;
            int nn = (tid & 7) << 3;
            const float* src = W + (size_t)(k0 + kk) * D + n0 + nn;
            float4 v0 = *(const float4*)src;
            float4 v1 = *(const float4*)(src + 4);
            ws[kk][nn + 0] = v0.x; ws[kk][nn + 1] = v0.y; ws[kk][nn + 2] = v0.z; ws[kk][nn + 3] = v0.w;
            ws[kk][nn + 4] = v1.x; ws[kk][nn + 5] = v1.y; ws[kk][nn + 6] = v1.z; ws[kk][nn + 7] = v1.w;
        }
        __syncthreads();
        int n = tid >> 2;
        int kq = (tid & 3) << 3;
        short8 hv;
#pragma unroll
        for (int j = 0; j < 8; ++j) {
            hv[j] = (short)f2bf(ws[kq + j][n]);
        }
        *(short8*)(WhT + (size_t)(n0 + n) * KD + k0 + kq) = hv;
    } else {
        // ---- ffout: 2 m per block (exact fp32 fourier part)
        int m = ((blk - 384) << 1) + (tid >> 7);
        int n4 = (tid & 127) << 2;
        float pos = (float)m * (1.0f / 511.0f);
        float4 acc = *(const float4*)(bias + n4);
#pragma unroll
        for (int j = 0; j < 16; ++j) {
            float freq = expf(0.46051701859880914f * (float)j);  // 1000^(j/15)
            float ang = pos * freq;
            float s = sinf(ang), c = cosf(ang);
            float4 wsn = *(const float4*)(W + (size_t)(D + j) * D + n4);
            float4 wcn = *(const float4*)(W + (size_t)(D + 16 + j) * D + n4);
            acc.x += s * wsn.x + c * wcn.x;
            acc.y += s * wsn.y + c * wcn.y;
            acc.z += s * wsn.z + c * wcn.z;
            acc.w += s * wsn.w + c * wcn.w;
        }
        *(float4*)(ffout + (size_t)m * D + n4) = acc;
    }
}

// ================= KB: segment means -> X [4096][512] bf16 ==================
// Mid-range coarse sum: Sum gsum[gcs..gce) directly (prefix difference
// algebraically cancels) — avg ~21 L2 rows instead of ~42, shorter chain.
__global__ __launch_bounds__(128) void k_buildx(const float* __restrict__ fe,
                                                const int* __restrict__ bounds,
                                                const float* __restrict__ cp,
                                                const float* __restrict__ gsum,
                                                short* __restrict__ X) {
    int bm = blockIdx.x;
    int b = bm >> 9;                            // bm / M
    int b0 = bounds[bm * 2 + 0];
    int b1 = bounds[bm * 2 + 1];
    int s = min(max(b0, 0), T - 1);
    int e = max(min(b1, T), s + 1);
    int cs_ = s >> 2, ce = e >> 2;
    int gcs = cs_ >> 5, gce = ce >> 5;          // coarse group indices (<= 64)
    int d4 = threadIdx.x << 2;

    const float* cpb = cp + (size_t)b * NCHUNK * D;
    const float* gsb = gsum + (size_t)b * NGRP * D + d4;

    // sum of full coarse groups strictly inside [gcs, gce)
    float4 acc = {0.f, 0.f, 0.f, 0.f};
    for (int g = gcs; g < gce; ++g) {
        float4 v = *(const float4*)(gsb + (size_t)g * D);
        acc.x += v.x; acc.y += v.y; acc.z += v.z; acc.w += v.w;
    }
    // partial-group chunk prefixes at the two edges
    if (ce & 31) {
        float4 v = *(const float4*)(cpb + (size_t)(ce - 1) * D + d4);
        acc.x += v.x; acc.y += v.y; acc.z += v.z; acc.w += v.w;
    }
    if (cs_ & 31) {
        float4 v = *(const float4*)(cpb + (size_t)(cs_ - 1) * D + d4);
        acc.x -= v.x; acc.y -= v.y; acc.z -= v.z; acc.w -= v.w;
    }

    const float* feb = fe + (size_t)b * T * D + d4;
    for (int t = ce * CHUNK; t < e; ++t) {           // <= 3 iters
        float4 v = *(const float4*)(feb + (size_t)t * D);
        acc.x += v.x; acc.y += v.y; acc.z += v.z; acc.w += v.w;
    }
    for (int t = cs_ * CHUNK; t < s; ++t) {          // <= 3 iters
        float4 v = *(const float4*)(feb + (size_t)t * D);
        acc.x -= v.x; acc.y -= v.y; acc.z -= v.z; acc.w -= v.w;
    }
    float inv = 1.0f / (float)(e - s);
    short4v hv;
    hv[0] = (short)f2bf(acc.x * inv);
    hv[1] = (short)f2bf(acc.y * inv);
    hv[2] = (short)f2bf(acc.z * inv);
    hv[3] = (short)f2bf(acc.w * inv);
    *(short4v*)(X + (size_t)bm * KD + d4) = hv;
}

// ================= KC: MFMA GEMM, Out = X@W + ffout =========================
// 64x64 block tile, 256 threads (2x2 waves of 32x32), K=512, single bf16.
#define BK 64
__global__ __launch_bounds__(256) void k_gemm(const short* __restrict__ X,
                                              const short* __restrict__ WhT,
                                              const float* __restrict__ ffout,
                                              float* __restrict__ out) {
    __shared__ short Ah[2][64 * 32];
    __shared__ short Bh[2][64 * 32];                 // 16 KB total
    int n0 = (blockIdx.x & 7) << 6;
    int m0 = (blockIdx.x >> 3) << 6;
    int tid = threadIdx.x;
    int w = tid >> 6;
    int l = tid & 63;
    int lm = l & 15;
    int q = l >> 4;
    int wm = (w & 1) << 5;
    int wn = (w >> 1) << 5;

    floatx4 acc[2][2];
#pragma unroll
    for (int i = 0; i < 2; ++i)
#pragma unroll
        for (int j = 0; j < 2; ++j)
            acc[i][j] = (floatx4){0.f, 0.f, 0.f, 0.f};

    int srow = tid >> 2;
    int skq = tid & 3;
    int sslot = skq ^ ((srow >> 1) & 3);
    int ldsoff = (srow << 5) + (sslot << 3);
    const short* gX = X + (size_t)(m0 + srow) * KD + (skq << 3);
    const short* gB = WhT + (size_t)(n0 + srow) * KD + (skq << 3);

    int aoff[2], boff[2];
#pragma unroll
    for (int mt = 0; mt < 2; ++mt) {
        int row = wm + (mt << 4) + lm;
        aoff[mt] = (row << 5) + ((q ^ ((row >> 1) & 3)) << 3);
    }
#pragma unroll
    for (int nt = 0; nt < 2; ++nt) {
        int row = wn + (nt << 4) + lm;
        boff[nt] = (row << 5) + ((q ^ ((row >> 1) & 3)) << 3);
    }

    // prologue prefetch: K-tile 0 (both 32-k halves)
    short8 pxh[2], pbh[2];
#pragma unroll
    for (int h = 0; h < 2; ++h) {
        pxh[h] = *(const short8*)(gX + (h << 5));
        pbh[h] = *(const short8*)(gB + (h << 5));
    }

    for (int k0 = 0; k0 < KD; k0 += BK) {   // 8 iterations
        __syncthreads();
#pragma unroll
        for (int h = 0; h < 2; ++h) {
            *(short8*)(&Ah[h][ldsoff]) = pxh[h];
            *(short8*)(&Bh[h][ldsoff]) = pbh[h];
        }
        __syncthreads();

        // prefetch next K-tile while computing this one
        int kn = k0 + BK;
        if (kn < KD) {
#pragma unroll
            for (int h = 0; h < 2; ++h) {
                pxh[h] = *(const short8*)(gX + kn + (h << 5));
                pbh[h] = *(const short8*)(gB + kn + (h << 5));
            }
        }

#pragma unroll
        for (int h = 0; h < 2; ++h) {
            short8 ah[2], bh[2];
#pragma unroll
            for (int mt = 0; mt < 2; ++mt)
                ah[mt] = *(const short8*)(&Ah[h][aoff[mt]]);
#pragma unroll
            for (int nt = 0; nt < 2; ++nt)
                bh[nt] = *(const short8*)(&Bh[h][boff[nt]]);
#pragma unroll
            for (int mt = 0; mt < 2; ++mt)
#pragma unroll
                for (int nt = 0; nt < 2; ++nt)
                    acc[mt][nt] = __builtin_amdgcn_mfma_f32_16x16x32_bf16(
                        ah[mt], bh[nt], acc[mt][nt], 0, 0, 0);
        }
    }

#pragma unroll
    for (int mt = 0; mt < 2; ++mt) {
#pragma unroll
        for (int nt = 0; nt < 2; ++nt) {
            int gcol = n0 + wn + (nt << 4) + lm;
#pragma unroll
            for (int r = 0; r < 4; ++r) {
                int grow = m0 + wm + (mt << 4) + (q << 2) + r;
                float f = ffout[(size_t)(grow & (M - 1)) * D + gcol];
                out[(size_t)grow * D + gcol] = acc[mt][nt][r] + f;
            }
        }
    }
}

extern "C" void kernel_launch(void* const* d_in, const int* in_sizes, int n_in,
                              void* d_out, int out_size, void* d_ws, size_t ws_size,
                              hipStream_t stream) {
    const float* fe = (const float*)d_in[0];
    const int* bounds = (const int*)d_in[1];
    const float* W = (const float*)d_in[2];
    const float* bias = (const float*)d_in[3];
    float* out = (float*)d_out;

    float* cp = (float*)d_ws;                                  // 33.5 MB
    float* gsum = cp + (size_t)B * NCHUNK * D;                 // 1 MB
    float* ffout = gsum + (size_t)B * NGRP * D;                // 1 MB
    short* X = (short*)(ffout + (size_t)M * D);                // 4 MB
    short* WhT = X + (size_t)BM * KD;                          // 0.5 MB

    k_fusedA<<<640, 256, 0, stream>>>(fe, W, bias, cp, gsum, WhT, ffout);
    k_buildx<<<BM, 128, 0, stream>>>(fe, bounds, cp, gsum, X);
    k_gemm<<<64 * 8, 256, 0, stream>>>(X, WhT, ffout, out);
}